// Round 4
// baseline (151.957 us; speedup 1.0000x reference)
//
#include <hip/hip_runtime.h>
#include <hip/hip_cooperative_groups.h>

namespace cg = cooperative_groups;

#define IN_DIM   256
#define OUT_DIM  128
#define IN_SEQ   512
#define OUT_SEQ  512
#define NUM_BASIS 16
#define LN_EPS   1e-5f

__device__ __forceinline__ float cosrev(float x) {
  // cos(2*pi*x): v_fract then v_cos (revolutions semantics)
  return __builtin_amdgcn_cosf(__builtin_amdgcn_fractf(x));
}

// ---------------------------------------------------------------------------
// One cooperative kernel, 512 blocks x 256 threads (= 2 blocks/CU on 256 CUs,
// co-resident by construction; ~130 VGPR < 256 budget at 8 waves/CU).
// Phase A: block b computes Z row b = x[b]@M.T + LayerNorm -> Zn, ZT.
// Phase B: block b = (i = b&127, kchunk = b>>7 of 128 k). Chebyshev recurrence
//          c(k+1)=2cos(2pi/p)c(k)-c(k-1) per (j,g); thread=(j, k-half of 64).
//          Groups of 8 k-steps; butterfly reduce batched over 8 values (ILP).
// Phase C: block b = output row s: out[s,:] = sum_k L[k,s] * V[k,:].
// Two grid.sync()s replace two kernel-launch boundaries (~10us/node).
// ---------------------------------------------------------------------------
__global__ __launch_bounds__(256, 2) void fused(
    const float* __restrict__ x, const float* __restrict__ M,
    const float* __restrict__ P, const float* __restrict__ L,
    const float* __restrict__ gamma, const float* __restrict__ beta,
    float* __restrict__ Zn, float* __restrict__ ZT,
    float* __restrict__ V, float* __restrict__ out) {
  cg::grid_group grid = cg::this_grid();
  const int b = blockIdx.x;
  const int t = threadIdx.x;

  __shared__ __align__(16) float xk[IN_DIM];
  __shared__ float redA[256];
  __shared__ float stats[8];
  __shared__ float redB[128 * 2];
  __shared__ float Lcol[IN_SEQ];
  __shared__ float redC[2 * OUT_DIM];

  // ========================= Phase A: Z + LayerNorm =========================
  {
    const int k = b;
    xk[t] = x[k * IN_DIM + t];
    __syncthreads();

    const int j = t & 127;
    const int h = t >> 7;
    const float4* __restrict__ M4 =
        reinterpret_cast<const float4*>(M + j * IN_DIM + h * 128);
    const float4* __restrict__ x4 = reinterpret_cast<const float4*>(xk + h * 128);
    float acc = 0.f;
#pragma unroll 8
    for (int c = 0; c < 32; ++c) {
      float4 m = M4[c];
      float4 xv = x4[c];
      acc = fmaf(m.x, xv.x, acc);
      acc = fmaf(m.y, xv.y, acc);
      acc = fmaf(m.z, xv.z, acc);
      acc = fmaf(m.w, xv.w, acc);
    }
    redA[t] = acc;
    __syncthreads();

    float z = 0.f;
    if (t < 128) z = redA[t] + redA[t + 128];

    float s1 = (t < 128) ? z : 0.f;
    float s2 = (t < 128) ? z * z : 0.f;
#pragma unroll
    for (int m = 1; m < 64; m <<= 1) {
      s1 += __shfl_xor(s1, m);
      s2 += __shfl_xor(s2, m);
    }
    const int w = t >> 6;
    if ((t & 63) == 0) {
      stats[w] = s1;
      stats[4 + w] = s2;
    }
    __syncthreads();
    const float mu  = (stats[0] + stats[1] + stats[2] + stats[3]) * (1.f / 128.f);
    const float msq = (stats[4] + stats[5] + stats[6] + stats[7]) * (1.f / 128.f);
    const float rs  = rsqrtf(msq - mu * mu + LN_EPS);

    if (t < 128) {
      float zn = (z - mu) * rs * gamma[t] + beta[t];
      Zn[k * OUT_DIM + t] = zn;
      ZT[t * IN_SEQ + k] = z;
    }
  }

  grid.sync();

  // ================= Phase B: Chebyshev position transform ==================
  {
    const int i     = b & 127;
    const int chunk = b >> 7;            // 0..3 (128 k each)
    const int j     = t & 127;
    const int kh    = t >> 7;            // k-half within chunk
    const int w01   = (t >> 6) & 1;      // wave parity within half
    const int ks0   = chunk * 128 + kh * 64;

    float Pv[NUM_BASIS], tc[NUM_BASIS], c0[NUM_BASIS], c1[NUM_BASIS];
    {
      const float4* __restrict__ P4 =
          reinterpret_cast<const float4*>(P + (size_t)(i * OUT_DIM + j) * NUM_BASIS);
      float4 pl[4] = {P4[0], P4[1], P4[2], P4[3]};
#pragma unroll
      for (int q = 0; q < 4; ++q) {
        Pv[4 * q + 0] = pl[q].x;
        Pv[4 * q + 1] = pl[q].y;
        Pv[4 * q + 2] = pl[q].z;
        Pv[4 * q + 3] = pl[q].w;
      }
    }
    const int pb = i * (OUT_DIM * NUM_BASIS) + j * NUM_BASIS + 2;
    const float km1 = (float)(ks0 - 1);
    const float kcu = (float)ks0;
#pragma unroll
    for (int g = 0; g < NUM_BASIS; ++g) {
      float pinv = 1.0f / (float)(pb + g);          // p >= 2 -> pinv <= 0.5
      tc[g] = 2.0f * __builtin_amdgcn_cosf(pinv);   // 2*cos(2*pi/p)
      c0[g] = cosrev(km1 * pinv);
      c1[g] = cosrev(kcu * pinv);
    }

    const float* __restrict__ znj = Zn + j;
    float buf[8];
#pragma unroll
    for (int r = 0; r < 8; ++r) buf[r] = znj[(ks0 + r) * OUT_DIM];

    for (int kg = 0; kg < 8; ++kg) {
      float nbuf[8];
#pragma unroll
      for (int r = 0; r < 8; ++r) {
        // final group's prefetch may read past Zn into the adjacent ZT
        // workspace region (allocated; values unused).
        nbuf[r] = znj[(ks0 + (kg + 1) * 8 + r) * OUT_DIM];
      }
      float v[8];
#pragma unroll
      for (int r = 0; r < 8; ++r) {
        float s = 0.f;
#pragma unroll
        for (int g = 0; g < NUM_BASIS; ++g) s = fmaf(Pv[g], c1[g], s);
        v[r] = buf[r] * s;
#pragma unroll
        for (int g = 0; g < NUM_BASIS; ++g) {
          float cn = fmaf(tc[g], c1[g], -c0[g]);
          c0[g] = c1[g];
          c1[g] = cn;
        }
      }
      // butterfly reduce over 64 lanes, 8 independent values (latency hidden)
#pragma unroll
      for (int m = 1; m < 64; m <<= 1) {
#pragma unroll
        for (int r = 0; r < 8; ++r) v[r] += __shfl_xor(v[r], m);
      }
      if ((t & 63) == 0) {
#pragma unroll
        for (int r = 0; r < 8; ++r) redB[(kh * 64 + kg * 8 + r) * 2 + w01] = v[r];
      }
#pragma unroll
      for (int r = 0; r < 8; ++r) buf[r] = nbuf[r];
    }

    __syncthreads();
    if (t < 128) {
      const int k = chunk * 128 + t;
      V[k * OUT_DIM + i] = redB[t * 2] + redB[t * 2 + 1] + ZT[i * IN_SEQ + k];
    }
  }

  grid.sync();

  // ================= Phase C: out[s,:] = sum_k L[k,s] V[k,:] ================
  {
    const int s = b;
    const int i = t & 127;
    const int q = t >> 7;  // k-half (256 each)
    Lcol[t] = L[t * OUT_SEQ + s];
    Lcol[t + 256] = L[(t + 256) * OUT_SEQ + s];
    __syncthreads();

    const int kb0 = q * 256;
    float acc = 0.f;
#pragma unroll 8
    for (int kk = 0; kk < 256; ++kk) {
      const int k = kb0 + kk;
      acc = fmaf(Lcol[k], V[k * OUT_DIM + i], acc);
    }
    redC[q * OUT_DIM + i] = acc;
    __syncthreads();

    if (t < OUT_DIM) {
      out[s * OUT_DIM + t] = redC[t] + redC[OUT_DIM + t];
    }
  }
}

extern "C" void kernel_launch(void* const* d_in, const int* in_sizes, int n_in,
                              void* d_out, int out_size, void* d_ws, size_t ws_size,
                              hipStream_t stream) {
  const float* x      = (const float*)d_in[0];
  const float* M      = (const float*)d_in[1];
  const float* P      = (const float*)d_in[2];
  const float* Linker = (const float*)d_in[3];
  const float* gamma  = (const float*)d_in[4];
  const float* beta   = (const float*)d_in[5];
  // d_in[6] = periods (recomputed inline: p = i*2048 + j*16 + g + 2, exact in f32)
  float* out = (float*)d_out;

  float* ws = (float*)d_ws;
  float* Zn = ws;                        // 512*128
  float* ZT = ws + IN_SEQ * OUT_DIM;     // 128*512 (pre-LN Z, transposed)
  float* V  = ws + 2 * IN_SEQ * OUT_DIM; // 512*128 (T + Z)

  void* args[] = {(void*)&x, (void*)&M, (void*)&P, (void*)&Linker,
                  (void*)&gamma, (void*)&beta, (void*)&Zn, (void*)&ZT,
                  (void*)&V, (void*)&out};
  hipLaunchCooperativeKernel(reinterpret_cast<void*>(fused), dim3(512), dim3(256),
                             args, 0, stream);
}

// Round 5
// 43.813 us; speedup vs baseline: 3.4684x; 3.4684x over previous
//
#include <hip/hip_runtime.h>

#define IN_DIM   256
#define OUT_DIM  128
#define IN_SEQ   512
#define OUT_SEQ  512
#define NUM_BASIS 16
#define LN_EPS   1e-5f

__device__ __forceinline__ float cosrev(float x) {
  // cos(2*pi*x): v_fract then v_cos (revolutions semantics)
  return __builtin_amdgcn_cosf(__builtin_amdgcn_fractf(x));
}

// ---------------------------------------------------------------------------
// Kernel 1: Z = x @ M.T (one block per k), LayerNorm -> Zn, ZT.
// Also zero-initializes out (so kernel 2 can accumulate atomically; the
// dependency through the graph edge orders it before kernel 2).
// ---------------------------------------------------------------------------
__global__ __launch_bounds__(256) void k_prep(const float* __restrict__ x,
                                              const float* __restrict__ M,
                                              const float* __restrict__ gamma,
                                              const float* __restrict__ beta,
                                              float* __restrict__ Zn,
                                              float* __restrict__ ZT,
                                              float* __restrict__ out) {
  const int k = blockIdx.x;
  const int t = threadIdx.x;
  __shared__ __align__(16) float xk[IN_DIM];
  __shared__ float red[256];
  __shared__ float stats[8];

  xk[t] = x[k * IN_DIM + t];
  if (t < 128) out[k * OUT_DIM + t] = 0.f;   // zero-init for K2's atomics
  __syncthreads();

  const int j = t & 127;
  const int h = t >> 7;  // which half of the 256-dim input
  const float4* __restrict__ M4 =
      reinterpret_cast<const float4*>(M + j * IN_DIM + h * 128);
  const float4* __restrict__ x4 = reinterpret_cast<const float4*>(xk + h * 128);
  float acc = 0.f;
#pragma unroll 8
  for (int c = 0; c < 32; ++c) {
    float4 m = M4[c];
    float4 xv = x4[c];
    acc = fmaf(m.x, xv.x, acc);
    acc = fmaf(m.y, xv.y, acc);
    acc = fmaf(m.z, xv.z, acc);
    acc = fmaf(m.w, xv.w, acc);
  }
  red[t] = acc;
  __syncthreads();

  float z = 0.f;
  if (t < 128) z = red[t] + red[t + 128];

  float s1 = (t < 128) ? z : 0.f;
  float s2 = (t < 128) ? z * z : 0.f;
#pragma unroll
  for (int m = 1; m < 64; m <<= 1) {
    s1 += __shfl_xor(s1, m);
    s2 += __shfl_xor(s2, m);
  }
  const int w = t >> 6;
  if ((t & 63) == 0) {
    stats[w] = s1;
    stats[4 + w] = s2;
  }
  __syncthreads();
  const float mu  = (stats[0] + stats[1] + stats[2] + stats[3]) * (1.f / 128.f);
  const float msq = (stats[4] + stats[5] + stats[6] + stats[7]) * (1.f / 128.f);
  const float rs  = rsqrtf(msq - mu * mu + LN_EPS);

  if (t < 128) {
    float zn = (z - mu) * rs * gamma[t] + beta[t];
    Zn[k * OUT_DIM + t] = zn;     // coalesced
    ZT[t * IN_SEQ + k] = z;       // scattered 4B, tiny total
  }
}

// ---------------------------------------------------------------------------
// Kernel 2: fused position transform + sequence transform.
// Block = (chunk 0..3 of 128 k, output channel i). 256 threads = (j, k-half).
// Phase B: Chebyshev recurrence c(k+1)=2cos(2pi/p)c(k)-c(k-1) per (j,g),
//   16 g per thread in registers; 8-k-step groups so the 6-level butterfly
//   reduce over j runs on 8 independent values (latency hidden). V column
//   (T + pre-LN residual) lands in LDS only — never written to global.
// Phase C: out[s,i] += sum_{k in chunk} L[k,s] * vcol[k] for all 512 s;
//   one atomicAdd per (s,i,chunk) — 4 contenders per address.
// ---------------------------------------------------------------------------
__global__ __launch_bounds__(256) void k_bc(const float* __restrict__ P,
                                            const float* __restrict__ L,
                                            const float* __restrict__ Zn,
                                            const float* __restrict__ ZT,
                                            float* __restrict__ out) {
  const int chunk = blockIdx.x;     // 0..3, 128 k each
  const int i     = blockIdx.y;     // 0..127
  const int t     = threadIdx.x;
  const int j     = t & 127;
  const int kh    = t >> 7;         // k-half within chunk
  const int w01   = (t >> 6) & 1;   // j-half parity (wave within the k-half)
  const int ks0   = chunk * 128 + kh * 64;

  __shared__ float redB[128 * 2];
  __shared__ float vcol[128];

  // --- per-(i,j,g) state ---
  float Pv[NUM_BASIS], tc[NUM_BASIS], c0[NUM_BASIS], c1[NUM_BASIS];
  {
    const float4* __restrict__ P4 =
        reinterpret_cast<const float4*>(P + (size_t)(i * OUT_DIM + j) * NUM_BASIS);
    float4 pl[4] = {P4[0], P4[1], P4[2], P4[3]};
#pragma unroll
    for (int q = 0; q < 4; ++q) {
      Pv[4 * q + 0] = pl[q].x;
      Pv[4 * q + 1] = pl[q].y;
      Pv[4 * q + 2] = pl[q].z;
      Pv[4 * q + 3] = pl[q].w;
    }
  }
  const int pb = i * (OUT_DIM * NUM_BASIS) + j * NUM_BASIS + 2;
  const float km1 = (float)(ks0 - 1);
  const float kcu = (float)ks0;
#pragma unroll
  for (int g = 0; g < NUM_BASIS; ++g) {
    float pinv = 1.0f / (float)(pb + g);          // p >= 2 -> pinv <= 0.5
    tc[g] = 2.0f * __builtin_amdgcn_cosf(pinv);   // 2*cos(2*pi/p)
    c0[g] = cosrev(km1 * pinv);
    c1[g] = cosrev(kcu * pinv);
  }

  // --- Phase B: 64 serial k-steps (8 groups of 8) ---
  const float* __restrict__ znj = Zn + j;
  float buf[8];
#pragma unroll
  for (int r = 0; r < 8; ++r) buf[r] = znj[(ks0 + r) * OUT_DIM];

  for (int kg = 0; kg < 8; ++kg) {
    float nbuf[8];
#pragma unroll
    for (int r = 0; r < 8; ++r) {
      // final group's prefetch reads past Zn into the adjacent ZT workspace
      // region (allocated; values unused).
      nbuf[r] = znj[(ks0 + (kg + 1) * 8 + r) * OUT_DIM];
    }
    float v[8];
#pragma unroll
    for (int r = 0; r < 8; ++r) {
      float s = 0.f;
#pragma unroll
      for (int g = 0; g < NUM_BASIS; ++g) s = fmaf(Pv[g], c1[g], s);
      v[r] = buf[r] * s;
#pragma unroll
      for (int g = 0; g < NUM_BASIS; ++g) {
        float cn = fmaf(tc[g], c1[g], -c0[g]);
        c0[g] = c1[g];
        c1[g] = cn;
      }
    }
#pragma unroll
    for (int m = 1; m < 64; m <<= 1) {
#pragma unroll
      for (int r = 0; r < 8; ++r) v[r] += __shfl_xor(v[r], m);
    }
    if ((t & 63) == 0) {
#pragma unroll
      for (int r = 0; r < 8; ++r) redB[(kh * 64 + kg * 8 + r) * 2 + w01] = v[r];
    }
#pragma unroll
    for (int r = 0; r < 8; ++r) buf[r] = nbuf[r];
  }

  __syncthreads();
  if (t < 128) {
    const int k = chunk * 128 + t;
    vcol[t] = redB[t * 2] + redB[t * 2 + 1] + ZT[i * IN_SEQ + k];
  }
  __syncthreads();

  // --- Phase C: rank-128 update of out column i ---
  const float* __restrict__ Lb = L + (size_t)chunk * 128 * OUT_SEQ;
  float acc0 = 0.f, acc1 = 0.f;
#pragma unroll 4
  for (int kk = 0; kk < 128; ++kk) {
    const float v = vcol[kk];                 // LDS broadcast
    acc0 = fmaf(Lb[kk * OUT_SEQ + t], v, acc0);        // s = t
    acc1 = fmaf(Lb[kk * OUT_SEQ + t + 256], v, acc1);  // s = t + 256
  }
  atomicAdd(&out[t * OUT_DIM + i], acc0);
  atomicAdd(&out[(t + 256) * OUT_DIM + i], acc1);
}

extern "C" void kernel_launch(void* const* d_in, const int* in_sizes, int n_in,
                              void* d_out, int out_size, void* d_ws, size_t ws_size,
                              hipStream_t stream) {
  const float* x      = (const float*)d_in[0];
  const float* M      = (const float*)d_in[1];
  const float* P      = (const float*)d_in[2];
  const float* Linker = (const float*)d_in[3];
  const float* gamma  = (const float*)d_in[4];
  const float* beta   = (const float*)d_in[5];
  // d_in[6] = periods (recomputed inline: p = i*2048 + j*16 + g + 2, exact in f32)
  float* out = (float*)d_out;

  float* ws = (float*)d_ws;
  float* Zn = ws;                        // 512*128
  float* ZT = ws + IN_SEQ * OUT_DIM;     // 128*512 (pre-LN Z, transposed)

  k_prep<<<dim3(IN_SEQ), dim3(256), 0, stream>>>(x, M, gamma, beta, Zn, ZT, out);
  k_bc<<<dim3(4, OUT_DIM), dim3(256), 0, stream>>>(P, Linker, Zn, ZT, out);
}